// Round 8
// baseline (3516.561 us; speedup 1.0000x reference)
//
#include <hip/hip_runtime.h>
#include <hip/hip_bf16.h>
#include <stdint.h>

#define HW      64
#define CIN     512
#define KOUT    512
#define BATCH   8
#define NANCH   9
#define NBOX    (HW*HW*NANCH)   /* 36864 */
#define PRE_NMS 6000
#define POST_NMS 300
#define SORT_N  8192

// ---------------------------------------------------------------------------
// Kernel 0: weight transpose  w[k][j] (j = ci*9+tap, 4608) -> wt[j][k]
// 32x32 LDS-tiled; both sides coalesced.  grid (144, 16), block 256.
// ---------------------------------------------------------------------------
__global__ __launch_bounds__(256)
void transpose_w(const float* __restrict__ w, float* __restrict__ wt) {
    __shared__ float t[32][33];
    const int jt = blockIdx.x * 32, kt = blockIdx.y * 32;
    const int c  = threadIdx.x & 31, r8 = threadIdx.x >> 5;
#pragma unroll
    for (int p = 0; p < 4; ++p) {
        int kl = r8 + p * 8;
        t[kl][c] = w[(size_t)(kt + kl) * 4608 + jt + c];
    }
    __syncthreads();
#pragma unroll
    for (int p = 0; p < 4; ++p) {
        int jl = r8 + p * 8;
        wt[(size_t)(jt + jl) * 512 + kt + c] = t[c][jl];
    }
}

// ---------------------------------------------------------------------------
// Kernel 1: 3x3 conv (pad=1) + bias + ReLU.  fp32 vector-FMA implicit GEMM.
// WG tile: 8 rows x 64 cols x 64 out-ch.  Per-thread: 4 rows x 8 ch x 4 x.
// Per-output accumulation order (cc-chunks of 8, ci 0..7, dy, dx, serial
// fp32 fmaf) is BIT-IDENTICAL to R1/R6/R7 passing kernels.
// Staging: double-buffered LDS; all writes contiguous ds_write_b128
// (weights from pre-transposed wt); input halo handled by predicated
// scalar reads (edge cols are always zero).  One barrier per chunk.
// ---------------------------------------------------------------------------
__global__ __launch_bounds__(256, 2)
void conv3x3_relu(const float* __restrict__ in, const float* __restrict__ wt,
                  const float* __restrict__ bias, float* __restrict__ feat) {
    __shared__ float s_in[2][8][10][64];   // [buf][ci][row y0-1..y0+8][x]
    __shared__ float s_w[2][72][64];       // [buf][j=ci*9+tap][k]

    const int tid = threadIdx.x;
    const int k0  = blockIdx.x * 64;
    const int y0  = blockIdx.y * 8;
    const int b   = blockIdx.z;
    const int kg  = tid & 7;          // 8 channel groups of 8
    const int pos = tid >> 3;         // 0..31
    const int tx  = pos & 15;         // x0 = tx*4
    const int ty  = pos >> 4;         // row block: rows ty*4 .. ty*4+3
    const int x0  = tx * 4;

    // ---- loop-invariant staging descriptors ----
    // input: 5 float4 slots over 8ci x 10r x 16c4  (1280 = 5*256 exactly)
    int in_lds[5]; int in_goff[5]; bool in_ok[5];
#pragma unroll
    for (int s = 0; s < 5; ++s) {
        int q  = tid + 256 * s;
        int ci = q / 160, rem = q % 160;
        int r  = rem >> 4, c4 = rem & 15;
        int gy = y0 - 1 + r;
        in_ok[s]  = ((unsigned)gy < 64u);
        int gyc   = gy < 0 ? 0 : (gy > 63 ? 63 : gy);
        in_lds[s] = (ci * 10 + r) * 64 + 4 * c4;
        in_goff[s] = ((b * 512 + ci) * 64 + gyc) * 64 + 4 * c4;  // + cc*4096
    }
    // weights: 5 float4 slots over 72j x 16k4 (1152; slot 4 ragged)
    int w_lds[5]; int w_goff[5]; bool w_ok[5];
#pragma unroll
    for (int s = 0; s < 5; ++s) {
        int q = tid + 256 * s;
        w_ok[s] = (q < 1152);
        int qq = w_ok[s] ? q : 0;
        int jl = qq / 16, k4 = qq % 16;
        w_lds[s]  = jl * 64 + 4 * k4;
        w_goff[s] = jl * 512 + k0 + 4 * k4;                      // + cc*4608
    }

    float4 pin[5], pw[5];
    const float4 z4 = make_float4(0.f, 0.f, 0.f, 0.f);
    auto prefetch = [&](int cc8) {
#pragma unroll
        for (int s = 0; s < 5; ++s)
            pin[s] = in_ok[s] ? *(const float4*)&in[in_goff[s] + cc8 * 32768] : z4;
#pragma unroll
        for (int s = 0; s < 5; ++s)
            if (w_ok[s]) pw[s] = *(const float4*)&wt[(size_t)cc8 * 36864 + w_goff[s]];
    };
    prefetch(0);

    float acc[4][8][4];
#pragma unroll
    for (int r = 0; r < 4; ++r)
#pragma unroll
        for (int k = 0; k < 8; ++k)
#pragma unroll
            for (int c = 0; c < 4; ++c) acc[r][k][c] = 0.0f;

    for (int cc8 = 0; cc8 < 64; ++cc8) {
        float* SIN = &s_in[cc8 & 1][0][0][0];
        float* SW  = &s_w[cc8 & 1][0][0];

        // staged regs -> LDS (all contiguous b128, conflict-free)
#pragma unroll
        for (int s = 0; s < 5; ++s)
            *(float4*)&SIN[in_lds[s]] = pin[s];     // OOB rows = zeros
#pragma unroll
        for (int s = 0; s < 5; ++s)
            if (w_ok[s]) *(float4*)&SW[w_lds[s]] = pw[s];
        __syncthreads();
        if (cc8 < 63) prefetch(cc8 + 1);   // latency hidden under compute

        // ---- compute: EXACT R1 FMA sequence per output ----
#pragma unroll
        for (int ci = 0; ci < 8; ++ci) {
#pragma unroll
            for (int dy = 0; dy < 3; ++dy) {
                float jv[4][6];
#pragma unroll
                for (int rr = 0; rr < 4; ++rr) {
                    int rw = ty * 4 + rr + dy;               // 0..9
                    const float* rp = &SIN[(ci * 10 + rw) * 64];
                    float4 va = *(const float4*)&rp[x0];     // gx x0..x0+3
                    int al = (tx > 0) ? (x0 - 1) : 0;
                    int ar = (tx < 15) ? (x0 + 4) : 0;
                    float lv = rp[al], rv = rp[ar];
                    jv[rr][0] = (tx > 0) ? lv : 0.0f;        // gx = x0-1
                    jv[rr][1] = va.x; jv[rr][2] = va.y;
                    jv[rr][3] = va.z; jv[rr][4] = va.w;
                    jv[rr][5] = (tx < 15) ? rv : 0.0f;       // gx = x0+4
                }
#pragma unroll
                for (int dx = 0; dx < 3; ++dx) {
                    const float* wp = &SW[(ci * 9 + dy * 3 + dx) * 64 + kg * 8];
                    float4 w0v = *(const float4*)wp;         // broadcast b128
                    float4 w1v = *(const float4*)(wp + 4);
                    float wv[8] = {w0v.x, w0v.y, w0v.z, w0v.w,
                                   w1v.x, w1v.y, w1v.z, w1v.w};
#pragma unroll
                    for (int rr = 0; rr < 4; ++rr)
#pragma unroll
                        for (int k = 0; k < 8; ++k)
#pragma unroll
                            for (int c = 0; c < 4; ++c)
                                acc[rr][k][c] = fmaf(jv[rr][dx + c], wv[k], acc[rr][k][c]);
                }
            }
        }
    }
    // bias + relu + store (float4 over x) — same chain as R1
#pragma unroll
    for (int k = 0; k < 8; ++k) {
        float bv = bias[k0 + kg * 8 + k];
#pragma unroll
        for (int rr = 0; rr < 4; ++rr) {
            int y = y0 + ty * 4 + rr;
            float4 o;
            o.x = fmaxf(acc[rr][k][0] + bv, 0.0f);
            o.y = fmaxf(acc[rr][k][1] + bv, 0.0f);
            o.z = fmaxf(acc[rr][k][2] + bv, 0.0f);
            o.w = fmaxf(acc[rr][k][3] + bv, 0.0f);
            *(float4*)&feat[(((size_t)b * KOUT + k0 + kg * 8 + k) * HW + y) * HW + x0] = o;
        }
    }
}

// ---------------------------------------------------------------------------
// Kernel 2: 1x1 cls+reg heads fused with softmax, box decode, clip, min-size
// filter and sortable-key packing.  One thread per pixel.  (R7 verbatim)
// ---------------------------------------------------------------------------
__global__ __launch_bounds__(256, 2)
void heads(const float* __restrict__ feat,
           const float* __restrict__ wcls, const float* __restrict__ bcls,
           const float* __restrict__ wreg, const float* __restrict__ breg,
           const float* __restrict__ iminfo,
           unsigned long long* __restrict__ keys, float4* __restrict__ pbox) {
    __shared__ float s_w[128 * 56];

    const int tid = threadIdx.x;
    const int pix = blockIdx.x * 256 + tid;
    const int b   = pix >> 12;
    const int rem = pix & 4095;
    const int y   = rem >> 6;
    const int x   = rem & 63;

    float acc[54];
#pragma unroll
    for (int j = 0; j < 54; ++j) acc[j] = 0.0f;

    for (int cc = 0; cc < 512; cc += 128) {
        __syncthreads();
        for (int i = tid; i < 128 * 54; i += 256) {
            int j = i / 128; int cl = i % 128;
            float v = (j < 18) ? wcls[(size_t)j * 512 + cc + cl]
                               : wreg[(size_t)(j - 18) * 512 + cc + cl];
            s_w[cl * 56 + j] = v;
        }
        __syncthreads();
#pragma unroll 8
        for (int c2 = 0; c2 < 128; ++c2) {
            float f = feat[(((size_t)b * 512 + cc + c2) * 64 + y) * 64 + x];
#pragma unroll
            for (int j = 0; j < 54; ++j)
                acc[j] = fmaf(f, s_w[c2 * 56 + j], acc[j]);
        }
    }

    const float im_h = iminfo[b * 3 + 0];
    const float im_w = iminfo[b * 3 + 1];
    const float ms   = 16.0f * iminfo[b * 3 + 2];
    const float ASP[3] = {0.5f, 1.0f, 2.0f};
    const float SCL[3] = {8.0f, 16.0f, 32.0f};

#pragma unroll
    for (int a = 0; a < 9; ++a) {
        float c0 = acc[2 * a]     + bcls[2 * a];
        float c1 = acc[2 * a + 1] + bcls[2 * a + 1];
        float m  = fmaxf(c0, c1);
        float e0 = expf(c0 - m), e1 = expf(c1 - m);
        float fg = e1 / (e0 + e1);

        float d0 = acc[18 + 4 * a + 0] + breg[4 * a + 0];
        float d1 = acc[18 + 4 * a + 1] + breg[4 * a + 1];
        float d2 = acc[18 + 4 * a + 2] + breg[4 * a + 2];
        float d3 = acc[18 + 4 * a + 3] + breg[4 * a + 3];

        int ai = a / 3, si = a % 3;
        float wsz = sqrtf(256.0f / ASP[ai]) * SCL[si];
        float hsz = sqrtf(256.0f * ASP[ai]) * SCL[si];
        float sx = (float)x * 16.0f, sy = (float)y * 16.0f;
        float x1a = sx + (7.5f - 0.5f * (wsz - 1.0f));
        float y1a = sy + (7.5f - 0.5f * (hsz - 1.0f));
        float x2a = sx + (7.5f + 0.5f * (wsz - 1.0f));
        float y2a = sy + (7.5f + 0.5f * (hsz - 1.0f));

        float wa = x2a - x1a + 1.0f, ha = y2a - y1a + 1.0f;
        float cxa = x1a + 0.5f * wa, cya = y1a + 0.5f * ha;
        float cx = d0 * wa + cxa, cy = d1 * ha + cya;
        float pw = expf(d2) * wa, ph = expf(d3) * ha;
        float bx1 = cx - 0.5f * pw, by1 = cy - 0.5f * ph;
        float bx2 = cx + 0.5f * pw, by2 = cy + 0.5f * ph;

        bx1 = fminf(fmaxf(bx1, 0.0f), im_w - 1.0f);
        by1 = fminf(fmaxf(by1, 0.0f), im_h - 1.0f);
        bx2 = fminf(fmaxf(bx2, 0.0f), im_w - 1.0f);
        by2 = fminf(fmaxf(by2, 0.0f), im_h - 1.0f);

        bool ok = (bx2 - bx1 + 1.0f >= ms) && (by2 - by1 + 1.0f >= ms);
        float s = ok ? fg : -1e9f;

        unsigned u = __float_as_uint(s);
        u = (u & 0x80000000u) ? ~u : (u | 0x80000000u);
        int idx = (y * 64 + x) * 9 + a;
        keys[(size_t)b * NBOX + idx] =
            ((unsigned long long)u << 32) | (unsigned)(~(unsigned)idx);
        pbox[(size_t)b * NBOX + idx] = make_float4(bx1, by1, bx2, by2);
    }
}

// ---------------------------------------------------------------------------
// Kernel 3: per-batch top-6000 via radix select + LDS bitonic sort. (R1)
// ---------------------------------------------------------------------------
__global__ __launch_bounds__(1024)
void select_sort(const unsigned long long* __restrict__ keys,
                 const float4* __restrict__ pbox,
                 float4* __restrict__ sorted) {
    __shared__ unsigned long long sbuf[SORT_N];
    __shared__ unsigned hist[16][256];
    __shared__ unsigned sh_prefix, sh_remaining, sh_counter;

    const int tid = threadIdx.x;
    const int b   = blockIdx.x;
    const int wv  = tid >> 6;
    const unsigned long long* kb = keys + (size_t)b * NBOX;

    if (tid == 0) { sh_prefix = 0u; sh_remaining = PRE_NMS; sh_counter = 0u; }

    for (int p = 3; p >= 0; --p) {
        for (int i = tid; i < 16 * 256; i += 1024) ((unsigned*)hist)[i] = 0u;
        __syncthreads();
        unsigned prefix = sh_prefix;
        unsigned pmask  = (p == 3) ? 0u : (0xFFFFFFFFu << (8 * (p + 1)));
        for (int i = tid; i < NBOX; i += 1024) {
            unsigned u = (unsigned)(kb[i] >> 32);
            if ((u & pmask) == prefix)
                atomicAdd(&hist[wv][(u >> (8 * p)) & 255], 1u);
        }
        __syncthreads();
        if (tid < 256) {
            unsigned s = 0;
#pragma unroll
            for (int w2 = 0; w2 < 16; ++w2) s += hist[w2][tid];
            hist[0][tid] = s;
        }
        __syncthreads();
        if (tid == 0) {
            unsigned rem = sh_remaining;
            int v = 255;
            for (; v > 0; --v) {
                unsigned c = hist[0][v];
                if (rem <= c) break;
                rem -= c;
            }
            sh_prefix    = prefix | ((unsigned)v << (8 * p));
            sh_remaining = rem;
        }
        __syncthreads();
    }
    const unsigned thr = sh_prefix;

    for (int i = tid; i < NBOX; i += 1024) {
        unsigned long long k = kb[i];
        bool act = ((unsigned)(k >> 32) >= thr);
        unsigned long long bal = __ballot(act);
        if (act) {
            int lane   = tid & 63;
            int leader = __ffsll(bal) - 1;
            unsigned base = 0;
            if (lane == leader) base = atomicAdd(&sh_counter, (unsigned)__popcll(bal));
            base = __shfl(base, leader);
            unsigned off = (unsigned)__popcll(bal & ((1ull << lane) - 1ull));
            unsigned pos2 = base + off;
            if (pos2 < SORT_N) sbuf[pos2] = k;
        }
    }
    __syncthreads();
    unsigned n = sh_counter; if (n > SORT_N) n = SORT_N;
    for (int i = (int)n + tid; i < SORT_N; i += 1024) sbuf[i] = 0ull;
    __syncthreads();

    for (int k = 2; k <= SORT_N; k <<= 1) {
        for (int j = k >> 1; j > 0; j >>= 1) {
            for (int t = tid; t < SORT_N / 2; t += 1024) {
                int i  = ((t & ~(j - 1)) << 1) | (t & (j - 1));
                int ix = i | j;
                bool up = ((i & k) == 0);
                unsigned long long a = sbuf[i], c = sbuf[ix];
                bool sw = up ? (a < c) : (a > c);
                if (sw) { sbuf[i] = c; sbuf[ix] = a; }
            }
            __syncthreads();
        }
    }

    for (int i = tid; i < PRE_NMS; i += 1024) {
        unsigned idx = ~((unsigned)sbuf[i]);
        sorted[(size_t)b * PRE_NMS + i] = pbox[(size_t)b * NBOX + idx];
    }
}

// ---------------------------------------------------------------------------
// Kernel 4: greedy NMS (argmax == find-first-set over validity bitmask). (R1)
// ---------------------------------------------------------------------------
__global__ __launch_bounds__(512, 2)
void nms(const float4* __restrict__ sorted, float* __restrict__ out) {
    __shared__ unsigned long long vmask[94];
    __shared__ int sh_j;

    const int tid = threadIdx.x;
    const int b   = blockIdx.x;
    const float4* sb = sorted + (size_t)b * PRE_NMS;

    float4 bx[12]; float ar[12];
#pragma unroll
    for (int s = 0; s < 12; ++s) {
        int i = tid + 512 * s;
        if (i < PRE_NMS) {
            float4 v = sb[i];
            bx[s] = v;
            ar[s] = (v.z - v.x + 1.0f) * (v.w - v.y + 1.0f);
        } else {
            bx[s] = make_float4(0.f, 0.f, 0.f, 0.f);
            ar[s] = 1.0f;
        }
    }
    if (tid < 94) vmask[tid] = (tid < 93) ? ~0ull : ((1ull << 48) - 1ull);
    __syncthreads();

    for (int it = 0; it < POST_NMS; ++it) {
        if (tid < 64) {
            unsigned long long w0 = vmask[tid];
            unsigned long long w1 = (tid < 30) ? vmask[tid + 64] : 0ull;
            int cand = w0 ? (tid * 64 + __ffsll(w0) - 1)
                          : (w1 ? ((tid + 64) * 64 + __ffsll(w1) - 1) : 0x7FFFFFFF);
#pragma unroll
            for (int off = 32; off > 0; off >>= 1) {
                int o = __shfl_xor(cand, off);
                cand = (o < cand) ? o : cand;
            }
            if (tid == 0) sh_j = (cand == 0x7FFFFFFF) ? 0 : cand;
        }
        __syncthreads();
        int j = sh_j;
        float4 jb = sb[j];
        if (tid == 0) {
            float* o = out + ((size_t)b * POST_NMS + it) * 5;
            o[0] = (float)b; o[1] = jb.x; o[2] = jb.y; o[3] = jb.z; o[4] = jb.w;
        }
        float ja = (jb.z - jb.x + 1.0f) * (jb.w - jb.y + 1.0f);
#pragma unroll
        for (int s = 0; s < 12; ++s) {
            int i = tid + 512 * s;
            if (i < PRE_NMS && ((vmask[i >> 6] >> (i & 63)) & 1ull)) {
                float xx1 = fmaxf(jb.x, bx[s].x);
                float yy1 = fmaxf(jb.y, bx[s].y);
                float xx2 = fminf(jb.z, bx[s].z);
                float yy2 = fminf(jb.w, bx[s].w);
                float inter = fmaxf(0.0f, xx2 - xx1 + 1.0f) *
                              fmaxf(0.0f, yy2 - yy1 + 1.0f);
                float iou = inter / (ja + ar[s] - inter);
                if (iou > 0.7f)
                    atomicAnd(&vmask[i >> 6], ~(1ull << (i & 63)));
            }
        }
        __syncthreads();
    }
}

// ---------------------------------------------------------------------------
extern "C" void kernel_launch(void* const* d_in, const int* in_sizes, int n_in,
                              void* d_out, int out_size, void* d_ws, size_t ws_size,
                              hipStream_t stream) {
    (void)in_sizes; (void)n_in; (void)out_size; (void)ws_size;
    const float* input  = (const float*)d_in[0];
    // d_in[1] = gt_box (unused)
    const float* iminfo = (const float*)d_in[2];
    const float* wfeat  = (const float*)d_in[3];
    const float* bfeat  = (const float*)d_in[4];
    const float* wcls   = (const float*)d_in[5];
    const float* bcls   = (const float*)d_in[6];
    const float* wreg   = (const float*)d_in[7];
    const float* breg   = (const float*)d_in[8];
    float* out = (float*)d_out;

    char* ws = (char*)d_ws;
    // layout: feat [0, 67.1MB); then a region shared in time:
    //   wt (9.44MB) lives ONLY until conv finishes; keys/pbox/sorted are
    //   written by heads/select AFTER conv -> safe aliasing.
    float*               feat   = (float*)ws;                                   // 67108864 B
    float*               wt     = (float*)(ws + 67108864);                      //  9437184 B (dead after conv)
    unsigned long long*  keys   = (unsigned long long*)(ws + 67108864);         //  2359296 B
    float4*              pbox   = (float4*)(ws + 67108864 + 2359296);           //  4718592 B
    float4*              sorted = (float4*)(ws + 67108864 + 2359296 + 4718592); //   768000 B

    transpose_w<<<dim3(144, 16), 256, 0, stream>>>(wfeat, wt);
    conv3x3_relu<<<dim3(8, 8, 8), 256, 0, stream>>>(input, wt, bfeat, feat);
    heads<<<dim3(128), 256, 0, stream>>>(feat, wcls, bcls, wreg, breg, iminfo, keys, pbox);
    select_sort<<<dim3(8), 1024, 0, stream>>>(keys, pbox, sorted);
    nms<<<dim3(8), 512, 0, stream>>>(sorted, out);
}

// Round 9
// 3174.870 us; speedup vs baseline: 1.1076x; 1.1076x over previous
//
#include <hip/hip_runtime.h>
#include <hip/hip_bf16.h>
#include <stdint.h>

#define HW      64
#define CIN     512
#define KOUT    512
#define BATCH   8
#define NANCH   9
#define NBOX    (HW*HW*NANCH)   /* 36864 */
#define PRE_NMS 6000
#define POST_NMS 300
#define SORT_N  8192

// ---------------------------------------------------------------------------
// Kernel 0: weight transpose  w[k][j] (j = ci*9+tap, 4608) -> wt[j][k]
// 32x32 LDS-tiled; both sides coalesced.  grid (144, 16), block 256.
// ---------------------------------------------------------------------------
__global__ __launch_bounds__(256)
void transpose_w(const float* __restrict__ w, float* __restrict__ wt) {
    __shared__ float t[32][33];
    const int jt = blockIdx.x * 32, kt = blockIdx.y * 32;
    const int c  = threadIdx.x & 31, r8 = threadIdx.x >> 5;
#pragma unroll
    for (int p = 0; p < 4; ++p) {
        int kl = r8 + p * 8;
        t[kl][c] = w[(size_t)(kt + kl) * 4608 + jt + c];
    }
    __syncthreads();
#pragma unroll
    for (int p = 0; p < 4; ++p) {
        int jl = r8 + p * 8;
        wt[(size_t)(jt + jl) * 512 + kt + c] = t[c][jl];
    }
}

// ---------------------------------------------------------------------------
// Kernel 1: 3x3 conv (pad=1) + bias + ReLU.  fp32 vector-FMA implicit GEMM.
// WG tile: 4 rows x 64 cols x 64 out-ch.  Per-thread: 2 rows x 8 ch x 4 x
// (acc = 64 VGPRs -> fits the 128-VGPR allocation, NO spill; R8 lesson).
// Per-output accumulation order (cc-chunks of 8, ci 0..7, dy, dx, serial
// fp32 fmaf) is BIT-IDENTICAL to R1/R6/R7 passing kernels.
// Staging: double-buffered LDS; ALL writes contiguous float4 (weights from
// pre-transposed wt -> zero bank conflicts, proven R8).  Input rows have a
// permanent zero-pad ring (stride 68, 4-elem lead pad) so halo reads are
// plain b32 loads, no predication.  One barrier per chunk.
// ---------------------------------------------------------------------------
__global__ __launch_bounds__(256, 2)
void conv3x3_relu(const float* __restrict__ in, const float* __restrict__ wt,
                  const float* __restrict__ bias, float* __restrict__ feat) {
    // input: 2 buffers x (8 ci x 6 rows x stride 68 + 4 lead pad)
    //   row cells 0..63 = gx 0..63 (re-staged per chunk);
    //   cells 64..67 + lead pad = PERMANENT zeros (halo; written once).
    __shared__ float s_in[2][8 * 6 * 68 + 4];
    __shared__ float s_w[2][72][64];       // [buf][j=ci*9+tap][k]

    const int tid = threadIdx.x;
    const int k0  = blockIdx.x * 64;
    const int y0  = blockIdx.y * 4;
    const int b   = blockIdx.z;
    const int kg  = tid & 7;          // 8 channel groups of 8
    const int pos = tid >> 3;         // 0..31
    const int tx  = pos & 15;         // x0 = tx*4
    const int ty  = pos >> 4;         // rows ty*2, ty*2+1
    const int x0  = tx * 4;

    // ---- loop-invariant staging descriptors ----
    // input: 3 float4 slots over 8ci x 6r x 16c4 (768 = 3*256 exactly)
    int in_lds[3]; int in_goff[3]; bool in_ok[3];
#pragma unroll
    for (int s = 0; s < 3; ++s) {
        int q  = tid + 256 * s;
        int ci = q / 96, rem = q % 96;
        int r  = rem >> 4, c4 = rem & 15;
        int gy = y0 - 1 + r;
        in_ok[s]  = ((unsigned)gy < 64u);
        int gyc   = gy < 0 ? 0 : (gy > 63 ? 63 : gy);
        in_lds[s] = 4 + (ci * 6 + r) * 68 + 4 * c4;
        in_goff[s] = ((b * 512 + ci) * 64 + gyc) * 64 + 4 * c4;  // + cc*4096
    }
    // weights: 5 float4 slots over 72j x 16k4 (1152; slot 4 ragged)
    int w_lds[5]; int w_goff[5]; bool w_ok[5];
#pragma unroll
    for (int s = 0; s < 5; ++s) {
        int q = tid + 256 * s;
        w_ok[s] = (q < 1152);
        int qq = w_ok[s] ? q : 0;
        int jl = qq / 16, k4 = qq % 16;
        w_lds[s]  = jl * 64 + 4 * k4;
        w_goff[s] = jl * 512 + k0 + 4 * k4;                      // + cc*4608
    }

    // zero input buffers once: establishes the permanent halo ring
    for (int i = tid; i < 2 * (8 * 6 * 68 + 4); i += 256) ((float*)s_in)[i] = 0.0f;
    __syncthreads();   // ring zeros visible before any staging write

    float4 pin[3], pw[5];
    const float4 z4 = make_float4(0.f, 0.f, 0.f, 0.f);
    auto prefetch = [&](int cc8) {
#pragma unroll
        for (int s = 0; s < 3; ++s)
            pin[s] = in_ok[s] ? *(const float4*)&in[in_goff[s] + cc8 * 32768] : z4;
#pragma unroll
        for (int s = 0; s < 5; ++s)
            if (w_ok[s]) pw[s] = *(const float4*)&wt[(size_t)cc8 * 36864 + w_goff[s]];
    };
    prefetch(0);

    float acc[2][8][4];
#pragma unroll
    for (int r = 0; r < 2; ++r)
#pragma unroll
        for (int k = 0; k < 8; ++k)
#pragma unroll
            for (int c = 0; c < 4; ++c) acc[r][k][c] = 0.0f;

    for (int cc8 = 0; cc8 < 64; ++cc8) {
        float* SIN = &s_in[cc8 & 1][0];
        float* SW  = &s_w[cc8 & 1][0][0];

        // staged regs -> LDS (contiguous float4, conflict-free; OOB rows = 0)
#pragma unroll
        for (int s = 0; s < 3; ++s)
            *(float4*)&SIN[in_lds[s]] = pin[s];
#pragma unroll
        for (int s = 0; s < 5; ++s)
            if (w_ok[s]) *(float4*)&SW[w_lds[s]] = pw[s];
        __syncthreads();
        if (cc8 < 63) prefetch(cc8 + 1);   // latency hidden under compute

        // ---- compute: EXACT R1 FMA sequence per output ----
#pragma unroll
        for (int ci = 0; ci < 8; ++ci) {
#pragma unroll
            for (int dy = 0; dy < 3; ++dy) {
                float iv[2][6];
#pragma unroll
                for (int rr = 0; rr < 2; ++rr) {
                    int rw = ty * 2 + rr + dy;               // 0..5
                    const float* rp = &SIN[4 + (ci * 6 + rw) * 68];
                    float4 va = *(const float4*)&rp[x0];     // gx x0..x0+3 (b128)
                    iv[rr][0] = rp[x0 - 1];                  // gx-1 (pad=0 at edge)
                    iv[rr][1] = va.x; iv[rr][2] = va.y;
                    iv[rr][3] = va.z; iv[rr][4] = va.w;
                    iv[rr][5] = rp[x0 + 4];                  // gx+4 (pad=0 at edge)
                }
#pragma unroll
                for (int dx = 0; dx < 3; ++dx) {
                    const float* wp = &SW[(ci * 9 + dy * 3 + dx) * 64 + kg * 8];
                    float4 w0v = *(const float4*)wp;         // broadcast b128
                    float4 w1v = *(const float4*)(wp + 4);
                    float wv[8] = {w0v.x, w0v.y, w0v.z, w0v.w,
                                   w1v.x, w1v.y, w1v.z, w1v.w};
#pragma unroll
                    for (int rr = 0; rr < 2; ++rr)
#pragma unroll
                        for (int k = 0; k < 8; ++k)
#pragma unroll
                            for (int c = 0; c < 4; ++c)
                                acc[rr][k][c] = fmaf(iv[rr][dx + c], wv[k], acc[rr][k][c]);
                }
            }
        }
    }
    // bias + relu + store (float4 over x) — identical chain to R1
#pragma unroll
    for (int k = 0; k < 8; ++k) {
        float bv = bias[k0 + kg * 8 + k];
#pragma unroll
        for (int rr = 0; rr < 2; ++rr) {
            int y = y0 + ty * 2 + rr;
            float4 o;
            o.x = fmaxf(acc[rr][k][0] + bv, 0.0f);
            o.y = fmaxf(acc[rr][k][1] + bv, 0.0f);
            o.z = fmaxf(acc[rr][k][2] + bv, 0.0f);
            o.w = fmaxf(acc[rr][k][3] + bv, 0.0f);
            *(float4*)&feat[(((size_t)b * KOUT + k0 + kg * 8 + k) * HW + y) * HW + x0] = o;
        }
    }
}

// ---------------------------------------------------------------------------
// Kernel 2: 1x1 cls+reg heads fused with softmax, box decode, clip, min-size
// filter and sortable-key packing.  One thread per pixel.  (R7 verbatim)
// ---------------------------------------------------------------------------
__global__ __launch_bounds__(256, 2)
void heads(const float* __restrict__ feat,
           const float* __restrict__ wcls, const float* __restrict__ bcls,
           const float* __restrict__ wreg, const float* __restrict__ breg,
           const float* __restrict__ iminfo,
           unsigned long long* __restrict__ keys, float4* __restrict__ pbox) {
    __shared__ float s_w[128 * 56];

    const int tid = threadIdx.x;
    const int pix = blockIdx.x * 256 + tid;
    const int b   = pix >> 12;
    const int rem = pix & 4095;
    const int y   = rem >> 6;
    const int x   = rem & 63;

    float acc[54];
#pragma unroll
    for (int j = 0; j < 54; ++j) acc[j] = 0.0f;

    for (int cc = 0; cc < 512; cc += 128) {
        __syncthreads();
        for (int i = tid; i < 128 * 54; i += 256) {
            int j = i / 128; int cl = i % 128;
            float v = (j < 18) ? wcls[(size_t)j * 512 + cc + cl]
                               : wreg[(size_t)(j - 18) * 512 + cc + cl];
            s_w[cl * 56 + j] = v;
        }
        __syncthreads();
#pragma unroll 8
        for (int c2 = 0; c2 < 128; ++c2) {
            float f = feat[(((size_t)b * 512 + cc + c2) * 64 + y) * 64 + x];
#pragma unroll
            for (int j = 0; j < 54; ++j)
                acc[j] = fmaf(f, s_w[c2 * 56 + j], acc[j]);
        }
    }

    const float im_h = iminfo[b * 3 + 0];
    const float im_w = iminfo[b * 3 + 1];
    const float ms   = 16.0f * iminfo[b * 3 + 2];
    const float ASP[3] = {0.5f, 1.0f, 2.0f};
    const float SCL[3] = {8.0f, 16.0f, 32.0f};

#pragma unroll
    for (int a = 0; a < 9; ++a) {
        float c0 = acc[2 * a]     + bcls[2 * a];
        float c1 = acc[2 * a + 1] + bcls[2 * a + 1];
        float m  = fmaxf(c0, c1);
        float e0 = expf(c0 - m), e1 = expf(c1 - m);
        float fg = e1 / (e0 + e1);

        float d0 = acc[18 + 4 * a + 0] + breg[4 * a + 0];
        float d1 = acc[18 + 4 * a + 1] + breg[4 * a + 1];
        float d2 = acc[18 + 4 * a + 2] + breg[4 * a + 2];
        float d3 = acc[18 + 4 * a + 3] + breg[4 * a + 3];

        int ai = a / 3, si = a % 3;
        float wsz = sqrtf(256.0f / ASP[ai]) * SCL[si];
        float hsz = sqrtf(256.0f * ASP[ai]) * SCL[si];
        float sx = (float)x * 16.0f, sy = (float)y * 16.0f;
        float x1a = sx + (7.5f - 0.5f * (wsz - 1.0f));
        float y1a = sy + (7.5f - 0.5f * (hsz - 1.0f));
        float x2a = sx + (7.5f + 0.5f * (wsz - 1.0f));
        float y2a = sy + (7.5f + 0.5f * (hsz - 1.0f));

        float wa = x2a - x1a + 1.0f, ha = y2a - y1a + 1.0f;
        float cxa = x1a + 0.5f * wa, cya = y1a + 0.5f * ha;
        float cx = d0 * wa + cxa, cy = d1 * ha + cya;
        float pw = expf(d2) * wa, ph = expf(d3) * ha;
        float bx1 = cx - 0.5f * pw, by1 = cy - 0.5f * ph;
        float bx2 = cx + 0.5f * pw, by2 = cy + 0.5f * ph;

        bx1 = fminf(fmaxf(bx1, 0.0f), im_w - 1.0f);
        by1 = fminf(fmaxf(by1, 0.0f), im_h - 1.0f);
        bx2 = fminf(fmaxf(bx2, 0.0f), im_w - 1.0f);
        by2 = fminf(fmaxf(by2, 0.0f), im_h - 1.0f);

        bool ok = (bx2 - bx1 + 1.0f >= ms) && (by2 - by1 + 1.0f >= ms);
        float s = ok ? fg : -1e9f;

        unsigned u = __float_as_uint(s);
        u = (u & 0x80000000u) ? ~u : (u | 0x80000000u);
        int idx = (y * 64 + x) * 9 + a;
        keys[(size_t)b * NBOX + idx] =
            ((unsigned long long)u << 32) | (unsigned)(~(unsigned)idx);
        pbox[(size_t)b * NBOX + idx] = make_float4(bx1, by1, bx2, by2);
    }
}

// ---------------------------------------------------------------------------
// Kernel 3: per-batch top-6000 via radix select + LDS bitonic sort. (R1)
// ---------------------------------------------------------------------------
__global__ __launch_bounds__(1024)
void select_sort(const unsigned long long* __restrict__ keys,
                 const float4* __restrict__ pbox,
                 float4* __restrict__ sorted) {
    __shared__ unsigned long long sbuf[SORT_N];
    __shared__ unsigned hist[16][256];
    __shared__ unsigned sh_prefix, sh_remaining, sh_counter;

    const int tid = threadIdx.x;
    const int b   = blockIdx.x;
    const int wv  = tid >> 6;
    const unsigned long long* kb = keys + (size_t)b * NBOX;

    if (tid == 0) { sh_prefix = 0u; sh_remaining = PRE_NMS; sh_counter = 0u; }

    for (int p = 3; p >= 0; --p) {
        for (int i = tid; i < 16 * 256; i += 1024) ((unsigned*)hist)[i] = 0u;
        __syncthreads();
        unsigned prefix = sh_prefix;
        unsigned pmask  = (p == 3) ? 0u : (0xFFFFFFFFu << (8 * (p + 1)));
        for (int i = tid; i < NBOX; i += 1024) {
            unsigned u = (unsigned)(kb[i] >> 32);
            if ((u & pmask) == prefix)
                atomicAdd(&hist[wv][(u >> (8 * p)) & 255], 1u);
        }
        __syncthreads();
        if (tid < 256) {
            unsigned s = 0;
#pragma unroll
            for (int w2 = 0; w2 < 16; ++w2) s += hist[w2][tid];
            hist[0][tid] = s;
        }
        __syncthreads();
        if (tid == 0) {
            unsigned rem = sh_remaining;
            int v = 255;
            for (; v > 0; --v) {
                unsigned c = hist[0][v];
                if (rem <= c) break;
                rem -= c;
            }
            sh_prefix    = prefix | ((unsigned)v << (8 * p));
            sh_remaining = rem;
        }
        __syncthreads();
    }
    const unsigned thr = sh_prefix;

    for (int i = tid; i < NBOX; i += 1024) {
        unsigned long long k = kb[i];
        bool act = ((unsigned)(k >> 32) >= thr);
        unsigned long long bal = __ballot(act);
        if (act) {
            int lane   = tid & 63;
            int leader = __ffsll(bal) - 1;
            unsigned base = 0;
            if (lane == leader) base = atomicAdd(&sh_counter, (unsigned)__popcll(bal));
            base = __shfl(base, leader);
            unsigned off = (unsigned)__popcll(bal & ((1ull << lane) - 1ull));
            unsigned pos2 = base + off;
            if (pos2 < SORT_N) sbuf[pos2] = k;
        }
    }
    __syncthreads();
    unsigned n = sh_counter; if (n > SORT_N) n = SORT_N;
    for (int i = (int)n + tid; i < SORT_N; i += 1024) sbuf[i] = 0ull;
    __syncthreads();

    for (int k = 2; k <= SORT_N; k <<= 1) {
        for (int j = k >> 1; j > 0; j >>= 1) {
            for (int t = tid; t < SORT_N / 2; t += 1024) {
                int i  = ((t & ~(j - 1)) << 1) | (t & (j - 1));
                int ix = i | j;
                bool up = ((i & k) == 0);
                unsigned long long a = sbuf[i], c = sbuf[ix];
                bool sw = up ? (a < c) : (a > c);
                if (sw) { sbuf[i] = c; sbuf[ix] = a; }
            }
            __syncthreads();
        }
    }

    for (int i = tid; i < PRE_NMS; i += 1024) {
        unsigned idx = ~((unsigned)sbuf[i]);
        sorted[(size_t)b * PRE_NMS + i] = pbox[(size_t)b * NBOX + idx];
    }
}

// ---------------------------------------------------------------------------
// Kernel 4: greedy NMS (argmax == find-first-set over validity bitmask). (R1)
// ---------------------------------------------------------------------------
__global__ __launch_bounds__(512, 2)
void nms(const float4* __restrict__ sorted, float* __restrict__ out) {
    __shared__ unsigned long long vmask[94];
    __shared__ int sh_j;

    const int tid = threadIdx.x;
    const int b   = blockIdx.x;
    const float4* sb = sorted + (size_t)b * PRE_NMS;

    float4 bx[12]; float ar[12];
#pragma unroll
    for (int s = 0; s < 12; ++s) {
        int i = tid + 512 * s;
        if (i < PRE_NMS) {
            float4 v = sb[i];
            bx[s] = v;
            ar[s] = (v.z - v.x + 1.0f) * (v.w - v.y + 1.0f);
        } else {
            bx[s] = make_float4(0.f, 0.f, 0.f, 0.f);
            ar[s] = 1.0f;
        }
    }
    if (tid < 94) vmask[tid] = (tid < 93) ? ~0ull : ((1ull << 48) - 1ull);
    __syncthreads();

    for (int it = 0; it < POST_NMS; ++it) {
        if (tid < 64) {
            unsigned long long w0 = vmask[tid];
            unsigned long long w1 = (tid < 30) ? vmask[tid + 64] : 0ull;
            int cand = w0 ? (tid * 64 + __ffsll(w0) - 1)
                          : (w1 ? ((tid + 64) * 64 + __ffsll(w1) - 1) : 0x7FFFFFFF);
#pragma unroll
            for (int off = 32; off > 0; off >>= 1) {
                int o = __shfl_xor(cand, off);
                cand = (o < cand) ? o : cand;
            }
            if (tid == 0) sh_j = (cand == 0x7FFFFFFF) ? 0 : cand;
        }
        __syncthreads();
        int j = sh_j;
        float4 jb = sb[j];
        if (tid == 0) {
            float* o = out + ((size_t)b * POST_NMS + it) * 5;
            o[0] = (float)b; o[1] = jb.x; o[2] = jb.y; o[3] = jb.z; o[4] = jb.w;
        }
        float ja = (jb.z - jb.x + 1.0f) * (jb.w - jb.y + 1.0f);
#pragma unroll
        for (int s = 0; s < 12; ++s) {
            int i = tid + 512 * s;
            if (i < PRE_NMS && ((vmask[i >> 6] >> (i & 63)) & 1ull)) {
                float xx1 = fmaxf(jb.x, bx[s].x);
                float yy1 = fmaxf(jb.y, bx[s].y);
                float xx2 = fminf(jb.z, bx[s].z);
                float yy2 = fminf(jb.w, bx[s].w);
                float inter = fmaxf(0.0f, xx2 - xx1 + 1.0f) *
                              fmaxf(0.0f, yy2 - yy1 + 1.0f);
                float iou = inter / (ja + ar[s] - inter);
                if (iou > 0.7f)
                    atomicAnd(&vmask[i >> 6], ~(1ull << (i & 63)));
            }
        }
        __syncthreads();
    }
}

// ---------------------------------------------------------------------------
extern "C" void kernel_launch(void* const* d_in, const int* in_sizes, int n_in,
                              void* d_out, int out_size, void* d_ws, size_t ws_size,
                              hipStream_t stream) {
    (void)in_sizes; (void)n_in; (void)out_size; (void)ws_size;
    const float* input  = (const float*)d_in[0];
    // d_in[1] = gt_box (unused)
    const float* iminfo = (const float*)d_in[2];
    const float* wfeat  = (const float*)d_in[3];
    const float* bfeat  = (const float*)d_in[4];
    const float* wcls   = (const float*)d_in[5];
    const float* bcls   = (const float*)d_in[6];
    const float* wreg   = (const float*)d_in[7];
    const float* breg   = (const float*)d_in[8];
    float* out = (float*)d_out;

    char* ws = (char*)d_ws;
    // layout: feat [0, 67.1MB); wt (9.44MB) aliases keys/pbox/sorted region:
    //   wt is dead after conv; keys/pbox/sorted written only after conv.
    float*               feat   = (float*)ws;                                   // 67108864 B
    float*               wt     = (float*)(ws + 67108864);                      //  9437184 B (dead after conv)
    unsigned long long*  keys   = (unsigned long long*)(ws + 67108864);         //  2359296 B
    float4*              pbox   = (float4*)(ws + 67108864 + 2359296);           //  4718592 B
    float4*              sorted = (float4*)(ws + 67108864 + 2359296 + 4718592); //   768000 B

    transpose_w<<<dim3(144, 16), 256, 0, stream>>>(wfeat, wt);
    conv3x3_relu<<<dim3(8, 16, 8), 256, 0, stream>>>(input, wt, bfeat, feat);
    heads<<<dim3(128), 256, 0, stream>>>(feat, wcls, bcls, wreg, breg, iminfo, keys, pbox);
    select_sort<<<dim3(8), 1024, 0, stream>>>(keys, pbox, sorted);
    nms<<<dim3(8), 512, 0, stream>>>(sorted, out);
}